// Round 4
// baseline (416.656 us; speedup 1.0000x reference)
//
#include <hip/hip_runtime.h>

#define IMG_H 480
#define IMG_W 640
#define IMG_B 4
#define HWSZ (IMG_H*IMG_W)
#define NPIX (IMG_B*HWSZ)   // 1228800, divisible by 256

typedef float __attribute__((ext_vector_type(2))) f32x2;

// ---------------- constants ----------------
// Normalized 11-tap Gaussian (sigma=1.5) for SSIM window (separable),
// constexpr so fully-unrolled loops fold them to inline literals.
constexpr float GW[11] = {
    0.00102838f, 0.00759878f, 0.03600077f, 0.10936067f, 0.21300555f,
    0.26601174f,
    0.21300555f, 0.10936067f, 0.03600077f, 0.00759878f, 0.00102838f};

// log2 of separable spatial weight for bilateral (sigma_space=8):
// log2(exp(-(k-5)^2/128)) = -(k-5)^2 / (128*ln2)
constexpr float LG2WS[11] = {
    -0.28177637f, -0.18033688f, -0.10143950f, -0.04508422f, -0.01127106f,
    0.0f,
    -0.01127106f, -0.04508422f, -0.10143950f, -0.18033688f, -0.28177637f};
// -200/ln2 (color term folded into exp2): exp(-200 d^2) = exp2(d^2 * C_COLOR)
#define C_COLOR (-288.53900818f)

__device__ inline float fexp2(float x) {
#if __has_builtin(__builtin_amdgcn_exp2f)
    return __builtin_amdgcn_exp2f(x);
#else
    return exp2f(x);
#endif
}

// ---------------- helpers ----------------
__device__ inline int refl(int i, int n) {
    // jnp.pad mode='reflect': -1 -> 1, n -> n-2 (valid for |overhang| <= 5 here)
    return i < 0 ? -i : (i >= n ? 2*n - 2 - i : i);
}

__device__ inline float sobel_abs(const float* __restrict__ p,
                                  int ym, int y0, int yp, int xm, int x0, int xp) {
    float a = p[ym*IMG_W+xm], b = p[ym*IMG_W+x0], c = p[ym*IMG_W+xp];
    float d = p[y0*IMG_W+xm],                      e = p[y0*IMG_W+xp];
    float f = p[yp*IMG_W+xm], g = p[yp*IMG_W+x0], h = p[yp*IMG_W+xp];
    float gx = (c + 2.f*e + h) - (a + 2.f*d + f);
    float gy = (a + 2.f*b + c) - (f + 2.f*g + h);
    return fabsf(gx) + fabsf(gy);
}

// ---------------- bilateral filter of IR ----------------
// 32x16 output tile per block, 2 x-adjacent pixels per thread (packed f32).
// LDS tile 26 rows x 42 cols; row stride 168 B (mult of 8) so even columns
// are 8B-aligned -> ds_read_b64 window loads.
__global__ __launch_bounds__(256)
void bilateral_kernel(const float* __restrict__ ir, float* __restrict__ bf) {
    __shared__ __attribute__((aligned(16))) float tile[26][42];
    const int tx = threadIdx.x, ty = threadIdx.y;          // 16 x 16
    const int x0 = blockIdx.x*32, y0 = blockIdx.y*16, b = blockIdx.z;
    const float* src = ir + b*HWSZ;
    const int tid = ty*16 + tx;
    for (int i = tid; i < 26*42; i += 256) {
        int r = i / 42, c = i % 42;
        int gy = refl(y0 - 5 + r, IMG_H);
        int gx = refl(x0 - 5 + c, IMG_W);
        tile[r][c] = src[gy*IMG_W + gx];
    }
    __syncthreads();

    const int px = 2*tx;                                    // local x of pixel pair
    f32x2 cen = { tile[ty+5][px+5], tile[ty+5][px+6] };
    f32x2 num = {0.f, 0.f}, den = {0.f, 0.f};
    #pragma unroll
    for (int dy = 0; dy < 11; ++dy) {
        // 12-float window rooted at even column px: 6 aligned 8B reads
        float w[12];
        #pragma unroll
        for (int k = 0; k < 6; ++k) {
            f32x2 p = *reinterpret_cast<const f32x2*>(&tile[ty+dy][px + 2*k]);
            w[2*k] = p.x; w[2*k+1] = p.y;
        }
        #pragma unroll
        for (int dx = 0; dx < 11; ++dx) {
            const float c2 = LG2WS[dy] + LG2WS[dx];
            f32x2 v = { w[dx], w[dx+1] };
            f32x2 d = v - cen;
            f32x2 arg = d*d*C_COLOR + c2;    // pk_mul + pk_fma (scalar bcast)
            f32x2 wt;
            wt.x = fexp2(arg.x);
            wt.y = fexp2(arg.y);
            num += wt*v;                     // pk_fma
            den += wt;                       // pk_add
        }
    }
    f32x2 res = num / den;
    *reinterpret_cast<f32x2*>(&bf[b*HWSZ + (y0+ty)*IMG_W + x0 + px]) = res;
}

// ---------------- SSIM (both pairs), separable Gaussian, zero padding ----------------
// 2 x-adjacent pixels per thread (packed f32). Block 16x8=128 threads,
// output tile 32x8. fields: 0:y 1:ir 2:g 3:y^2 4:ir^2 5:g^2 6:y*g 7:ir*g
__global__ __launch_bounds__(128)
void ssim_kernel(const float* __restrict__ vis, const float* __restrict__ ir,
                 const float* __restrict__ gen, float* __restrict__ accum) {
    __shared__ __attribute__((aligned(16))) float sy[18][42], si[18][42], sg[18][42];
    __shared__ __attribute__((aligned(16))) float hs[8][18][32];
    const int tx = threadIdx.x, ty = threadIdx.y;          // 16 x 8
    const int x0 = blockIdx.x*32, y0 = blockIdx.y*8, b = blockIdx.z;
    const int tid = ty*16 + tx;                            // 0..127
    const float* py = vis + b*3*HWSZ;   // channel 0 of vis = image_y
    const float* pi = ir  + b*HWSZ;
    const float* pg = gen + b*HWSZ;

    for (int i = tid; i < 42*18; i += 128) {
        int r = i / 42, c = i % 42;
        int gy = y0 - 5 + r, gx = x0 - 5 + c;
        bool ok = (gy >= 0) & (gy < IMG_H) & (gx >= 0) & (gx < IMG_W);
        int idx = ok ? gy*IMG_W + gx : 0;
        float vy = ok ? py[idx] : 0.f;
        float vi = ok ? pi[idx] : 0.f;
        float vg = ok ? pg[idx] : 0.f;
        sy[r][c] = vy; si[r][c] = vi; sg[r][c] = vg;
    }
    __syncthreads();

    // horizontal pass: 18 rows x 16 column-pairs, packed f32
    for (int i = tid; i < 18*16; i += 128) {
        int r = i / 16, c = 2*(i % 16);                    // c even, <= 30
        float wy[12], wi[12], wg[12];
        #pragma unroll
        for (int k = 0; k < 6; ++k) {                      // aligned 8B LDS reads
            f32x2 p0 = *reinterpret_cast<const f32x2*>(&sy[r][c + 2*k]);
            f32x2 p1 = *reinterpret_cast<const f32x2*>(&si[r][c + 2*k]);
            f32x2 p2 = *reinterpret_cast<const f32x2*>(&sg[r][c + 2*k]);
            wy[2*k] = p0.x; wy[2*k+1] = p0.y;
            wi[2*k] = p1.x; wi[2*k+1] = p1.y;
            wg[2*k] = p2.x; wg[2*k+1] = p2.y;
        }
        f32x2 a0={0,0},a1={0,0},a2={0,0},a3={0,0},a4={0,0},a5={0,0},a6={0,0},a7={0,0};
        #pragma unroll
        for (int dx = 0; dx < 11; ++dx) {
            const float g = GW[dx];
            f32x2 vy = { wy[dx], wy[dx+1] };
            f32x2 vi = { wi[dx], wi[dx+1] };
            f32x2 vg = { wg[dx], wg[dx+1] };
            f32x2 gy = g*vy, gi = g*vi, gg = g*vg;
            a0 += gy;    a1 += gi;    a2 += gg;
            a3 += gy*vy; a4 += gi*vi; a5 += gg*vg;
            a6 += gy*vg; a7 += gi*vg;
        }
        *reinterpret_cast<f32x2*>(&hs[0][r][c]) = a0;
        *reinterpret_cast<f32x2*>(&hs[1][r][c]) = a1;
        *reinterpret_cast<f32x2*>(&hs[2][r][c]) = a2;
        *reinterpret_cast<f32x2*>(&hs[3][r][c]) = a3;
        *reinterpret_cast<f32x2*>(&hs[4][r][c]) = a4;
        *reinterpret_cast<f32x2*>(&hs[5][r][c]) = a5;
        *reinterpret_cast<f32x2*>(&hs[6][r][c]) = a6;
        *reinterpret_cast<f32x2*>(&hs[7][r][c]) = a7;
    }
    __syncthreads();

    // vertical pass: one pixel-pair per thread
    const int px = 2*tx;
    f32x2 s[8];
    #pragma unroll
    for (int f = 0; f < 8; ++f) {
        f32x2 acc = {0.f, 0.f};
        #pragma unroll
        for (int dy = 0; dy < 11; ++dy)
            acc += GW[dy] * (*reinterpret_cast<const f32x2*>(&hs[f][ty+dy][px]));
        s[f] = acc;
    }
    const float C1 = 1e-4f, C2 = 9e-4f;
    f32x2 muY = s[0], muI = s[1], muG = s[2];
    f32x2 vY  = s[3] - muY*muY, vI = s[4] - muI*muI, vG = s[5] - muG*muG;
    f32x2 cYG = s[6] - muY*muG, cIG = s[7] - muI*muG;
    f32x2 ssimYG = ((2.f*muY*muG + C1)*(2.f*cYG + C2)) /
                   ((muY*muY + muG*muG + C1)*(vY + vG + C2));
    f32x2 ssimIG = ((2.f*muI*muG + C1)*(2.f*cIG + C2)) /
                   ((muI*muI + muG*muG + C1)*(vI + vG + C2));

    // block reduce (2 waves)
    float v0 = ssimYG.x + ssimYG.y, v1 = ssimIG.x + ssimIG.y;
    #pragma unroll
    for (int off = 32; off > 0; off >>= 1) {
        v0 += __shfl_down(v0, off);
        v1 += __shfl_down(v1, off);
    }
    __shared__ float red[2][2];
    int lane = tid & 63, wv = tid >> 6;
    if (lane == 0) { red[0][wv] = v0; red[1][wv] = v1; }
    __syncthreads();
    if (tid == 0) {
        atomicAdd(&accum[3], red[0][0]+red[0][1]);
        atomicAdd(&accum[4], red[1][0]+red[1][1]);
    }
}

// ---------------- Sobel-gradient loss + L1 losses ----------------
__global__ __launch_bounds__(256)
void grad_kernel(const float* __restrict__ vis, const float* __restrict__ ir,
                 const float* __restrict__ gen, const float* __restrict__ bf,
                 float* __restrict__ accum) {
    const int idx = blockIdx.x*256 + threadIdx.x;   // NPIX divisible by 256, no guard
    const int b = idx / HWSZ, rem = idx % HWSZ;
    const int y = rem / IMG_W, x = rem % IMG_W;
    const float* py = vis + b*3*HWSZ;
    const float* pi = ir  + b*HWSZ;
    const float* pg = gen + b*HWSZ;
    const float* pb = bf  + b*HWSZ;

    const int ym = (y == 0) ? 1 : y-1, yp = (y == IMG_H-1) ? IMG_H-2 : y+1;
    const int xm = (x == 0) ? 1 : x-1, xp = (x == IMG_W-1) ? IMG_W-2 : x+1;

    float yg = sobel_abs(py, ym, y, yp, xm, x, xp);
    float ig = sobel_abs(pb, ym, y, yp, xm, x, xp);
    float gg = sobel_abs(pg, ym, y, yp, xm, x, xp);
    float tgrad = fabsf(gg - fmaxf(yg, ig));

    float cy = py[y*IMG_W+x], ci = pi[y*IMG_W+x], cg = pg[y*IMG_W+x];
    float tin  = fabsf(cg - fmaxf(cy, ci));
    float ttra = fabsf(cg - 0.5f*(ci + cy));

    float v0 = tin, v1 = tgrad, v2 = ttra;
    #pragma unroll
    for (int off = 32; off > 0; off >>= 1) {
        v0 += __shfl_down(v0, off);
        v1 += __shfl_down(v1, off);
        v2 += __shfl_down(v2, off);
    }
    __shared__ float red[3][4];
    int lane = threadIdx.x & 63, wv = threadIdx.x >> 6;
    if (lane == 0) { red[0][wv] = v0; red[1][wv] = v1; red[2][wv] = v2; }
    __syncthreads();
    if (threadIdx.x == 0) {
        atomicAdd(&accum[0], red[0][0]+red[0][1]+red[0][2]+red[0][3]);
        atomicAdd(&accum[1], red[1][0]+red[1][1]+red[1][2]+red[1][3]);
        atomicAdd(&accum[2], red[2][0]+red[2][1]+red[2][2]+red[2][3]);
    }
}

// ---------------- finalize ----------------
__global__ void finalize_kernel(const float* __restrict__ accum, float* __restrict__ out) {
    if (threadIdx.x == 0) {
        const float inv = 1.0f / (float)NPIX;
        float lin   = accum[0] * inv;
        float lgrad = accum[1] * inv;
        float ltra  = accum[2] * inv;
        float ssim1 = accum[3] * inv;
        float ssim2 = accum[4] * inv;
        float lssim = (1.f - ssim1)*0.5f + (1.f - ssim2)*0.5f;
        float ltot  = 10.f*lin + 35.f*lgrad + 1.f*lssim + 10.f*ltra;
        out[0] = ltot; out[1] = lin; out[2] = lgrad; out[3] = lssim; out[4] = ltra;
    }
}

extern "C" void kernel_launch(void* const* d_in, const int* in_sizes, int n_in,
                              void* d_out, int out_size, void* d_ws, size_t ws_size,
                              hipStream_t stream) {
    const float* vis = (const float*)d_in[0];   // (4,3,480,640)
    const float* ir  = (const float*)d_in[1];   // (4,1,480,640)
    const float* gen = (const float*)d_in[2];   // (4,1,480,640)
    float* out = (float*)d_out;                 // 5 fp32 scalars

    float* accum = (float*)d_ws;                       // 5 accumulators (zeroed)
    float* bf    = (float*)((char*)d_ws + 256);        // bilateral output, NPIX floats

    hipMemsetAsync(d_ws, 0, 256, stream);

    dim3 blkB(16, 16);
    dim3 grdB(IMG_W/32, IMG_H/16, IMG_B);   // 20 x 30 x 4
    bilateral_kernel<<<grdB, blkB, 0, stream>>>(ir, bf);

    dim3 blkS(16, 8);
    dim3 grdS(IMG_W/32, IMG_H/8, IMG_B);    // 20 x 60 x 4
    ssim_kernel<<<grdS, blkS, 0, stream>>>(vis, ir, gen, accum);
    grad_kernel<<<NPIX/256, 256, 0, stream>>>(vis, ir, gen, bf, accum);
    finalize_kernel<<<1, 64, 0, stream>>>(accum, out);
}

// Round 5
// 144.062 us; speedup vs baseline: 2.8922x; 2.8922x over previous
//
#include <hip/hip_runtime.h>

#define IMG_H 480
#define IMG_W 640
#define IMG_B 4
#define HWSZ (IMG_H*IMG_W)
#define NPIX (IMG_B*HWSZ)   // 1228800, divisible by 256
#define NBLK 4800           // blocks per reduction kernel (20*60*4 and NPIX/256)

typedef float __attribute__((ext_vector_type(2))) f32x2;

// ---------------- constants ----------------
// Normalized 11-tap Gaussian (sigma=1.5) for SSIM window (separable),
// constexpr so fully-unrolled loops fold them to inline literals.
constexpr float GW[11] = {
    0.00102838f, 0.00759878f, 0.03600077f, 0.10936067f, 0.21300555f,
    0.26601174f,
    0.21300555f, 0.10936067f, 0.03600077f, 0.00759878f, 0.00102838f};

// log2 of separable spatial weight for bilateral (sigma_space=8):
// log2(exp(-(k-5)^2/128)) = -(k-5)^2 / (128*ln2)
constexpr float LG2WS[11] = {
    -0.28177637f, -0.18033688f, -0.10143950f, -0.04508422f, -0.01127106f,
    0.0f,
    -0.01127106f, -0.04508422f, -0.10143950f, -0.18033688f, -0.28177637f};
// -200/ln2 (color term folded into exp2): exp(-200 d^2) = exp2(d^2 * C_COLOR)
#define C_COLOR (-288.53900818f)

__device__ inline float fexp2(float x) {
#if __has_builtin(__builtin_amdgcn_exp2f)
    return __builtin_amdgcn_exp2f(x);
#else
    return exp2f(x);
#endif
}

// ---------------- helpers ----------------
__device__ inline int refl(int i, int n) {
    // jnp.pad mode='reflect': -1 -> 1, n -> n-2 (valid for |overhang| <= 5 here)
    return i < 0 ? -i : (i >= n ? 2*n - 2 - i : i);
}

__device__ inline float sobel_abs(const float* __restrict__ p,
                                  int ym, int y0, int yp, int xm, int x0, int xp) {
    float a = p[ym*IMG_W+xm], b = p[ym*IMG_W+x0], c = p[ym*IMG_W+xp];
    float d = p[y0*IMG_W+xm],                      e = p[y0*IMG_W+xp];
    float f = p[yp*IMG_W+xm], g = p[yp*IMG_W+x0], h = p[yp*IMG_W+xp];
    float gx = (c + 2.f*e + h) - (a + 2.f*d + f);
    float gy = (a + 2.f*b + c) - (f + 2.f*g + h);
    return fabsf(gx) + fabsf(gy);
}

// ---------------- bilateral filter of IR ----------------
// 32x16 output tile per block, 2 x-adjacent pixels per thread (packed f32).
__global__ __launch_bounds__(256)
void bilateral_kernel(const float* __restrict__ ir, float* __restrict__ bf) {
    __shared__ __attribute__((aligned(16))) float tile[26][42];
    const int tx = threadIdx.x, ty = threadIdx.y;          // 16 x 16
    const int x0 = blockIdx.x*32, y0 = blockIdx.y*16, b = blockIdx.z;
    const float* src = ir + b*HWSZ;
    const int tid = ty*16 + tx;
    for (int i = tid; i < 26*42; i += 256) {
        int r = i / 42, c = i % 42;
        int gy = refl(y0 - 5 + r, IMG_H);
        int gx = refl(x0 - 5 + c, IMG_W);
        tile[r][c] = src[gy*IMG_W + gx];
    }
    __syncthreads();

    const int px = 2*tx;                                    // local x of pixel pair
    f32x2 cen = { tile[ty+5][px+5], tile[ty+5][px+6] };
    f32x2 num = {0.f, 0.f}, den = {0.f, 0.f};
    #pragma unroll
    for (int dy = 0; dy < 11; ++dy) {
        // 12-float window rooted at even column px: 6 aligned 8B reads
        float w[12];
        #pragma unroll
        for (int k = 0; k < 6; ++k) {
            f32x2 p = *reinterpret_cast<const f32x2*>(&tile[ty+dy][px + 2*k]);
            w[2*k] = p.x; w[2*k+1] = p.y;
        }
        #pragma unroll
        for (int dx = 0; dx < 11; ++dx) {
            const float c2 = LG2WS[dy] + LG2WS[dx];
            f32x2 v = { w[dx], w[dx+1] };
            f32x2 d = v - cen;
            f32x2 arg = d*d*C_COLOR + c2;    // pk_mul + pk_fma (scalar bcast)
            f32x2 wt;
            wt.x = fexp2(arg.x);
            wt.y = fexp2(arg.y);
            num += wt*v;                     // pk_fma
            den += wt;                       // pk_add
        }
    }
    f32x2 res = num / den;
    *reinterpret_cast<f32x2*>(&bf[b*HWSZ + (y0+ty)*IMG_W + x0 + px]) = res;
}

// ---------------- SSIM (both pairs), separable Gaussian, zero padding ----------------
// 2 x-adjacent pixels per thread (packed f32). Block 16x8=128 threads,
// output tile 32x8. Partials (no atomics): parts[3]=ssimYG, parts[4]=ssimIG.
__global__ __launch_bounds__(128)
void ssim_kernel(const float* __restrict__ vis, const float* __restrict__ ir,
                 const float* __restrict__ gen, float* __restrict__ parts) {
    __shared__ __attribute__((aligned(16))) float sy[18][42], si[18][42], sg[18][42];
    __shared__ __attribute__((aligned(16))) float hs[8][18][32];
    const int tx = threadIdx.x, ty = threadIdx.y;          // 16 x 8
    const int x0 = blockIdx.x*32, y0 = blockIdx.y*8, b = blockIdx.z;
    const int tid = ty*16 + tx;                            // 0..127
    const int gid = blockIdx.x + 20*blockIdx.y + 1200*blockIdx.z;  // 0..4799
    const float* py = vis + b*3*HWSZ;   // channel 0 of vis = image_y
    const float* pi = ir  + b*HWSZ;
    const float* pg = gen + b*HWSZ;

    for (int i = tid; i < 42*18; i += 128) {
        int r = i / 42, c = i % 42;
        int gy = y0 - 5 + r, gx = x0 - 5 + c;
        bool ok = (gy >= 0) & (gy < IMG_H) & (gx >= 0) & (gx < IMG_W);
        int idx = ok ? gy*IMG_W + gx : 0;
        float vy = ok ? py[idx] : 0.f;
        float vi = ok ? pi[idx] : 0.f;
        float vg = ok ? pg[idx] : 0.f;
        sy[r][c] = vy; si[r][c] = vi; sg[r][c] = vg;
    }
    __syncthreads();

    // horizontal pass: 18 rows x 16 column-pairs, packed f32
    for (int i = tid; i < 18*16; i += 128) {
        int r = i / 16, c = 2*(i % 16);                    // c even, <= 30
        float wy[12], wi[12], wg[12];
        #pragma unroll
        for (int k = 0; k < 6; ++k) {                      // aligned 8B LDS reads
            f32x2 p0 = *reinterpret_cast<const f32x2*>(&sy[r][c + 2*k]);
            f32x2 p1 = *reinterpret_cast<const f32x2*>(&si[r][c + 2*k]);
            f32x2 p2 = *reinterpret_cast<const f32x2*>(&sg[r][c + 2*k]);
            wy[2*k] = p0.x; wy[2*k+1] = p0.y;
            wi[2*k] = p1.x; wi[2*k+1] = p1.y;
            wg[2*k] = p2.x; wg[2*k+1] = p2.y;
        }
        f32x2 a0={0,0},a1={0,0},a2={0,0},a3={0,0},a4={0,0},a5={0,0},a6={0,0},a7={0,0};
        #pragma unroll
        for (int dx = 0; dx < 11; ++dx) {
            const float g = GW[dx];
            f32x2 vy = { wy[dx], wy[dx+1] };
            f32x2 vi = { wi[dx], wi[dx+1] };
            f32x2 vg = { wg[dx], wg[dx+1] };
            f32x2 gy = g*vy, gi = g*vi, gg = g*vg;
            a0 += gy;    a1 += gi;    a2 += gg;
            a3 += gy*vy; a4 += gi*vi; a5 += gg*vg;
            a6 += gy*vg; a7 += gi*vg;
        }
        *reinterpret_cast<f32x2*>(&hs[0][r][c]) = a0;
        *reinterpret_cast<f32x2*>(&hs[1][r][c]) = a1;
        *reinterpret_cast<f32x2*>(&hs[2][r][c]) = a2;
        *reinterpret_cast<f32x2*>(&hs[3][r][c]) = a3;
        *reinterpret_cast<f32x2*>(&hs[4][r][c]) = a4;
        *reinterpret_cast<f32x2*>(&hs[5][r][c]) = a5;
        *reinterpret_cast<f32x2*>(&hs[6][r][c]) = a6;
        *reinterpret_cast<f32x2*>(&hs[7][r][c]) = a7;
    }
    __syncthreads();

    // vertical pass: one pixel-pair per thread
    const int px = 2*tx;
    f32x2 s[8];
    #pragma unroll
    for (int f = 0; f < 8; ++f) {
        f32x2 acc = {0.f, 0.f};
        #pragma unroll
        for (int dy = 0; dy < 11; ++dy)
            acc += GW[dy] * (*reinterpret_cast<const f32x2*>(&hs[f][ty+dy][px]));
        s[f] = acc;
    }
    const float C1 = 1e-4f, C2 = 9e-4f;
    f32x2 muY = s[0], muI = s[1], muG = s[2];
    f32x2 vY  = s[3] - muY*muY, vI = s[4] - muI*muI, vG = s[5] - muG*muG;
    f32x2 cYG = s[6] - muY*muG, cIG = s[7] - muI*muG;
    f32x2 ssimYG = ((2.f*muY*muG + C1)*(2.f*cYG + C2)) /
                   ((muY*muY + muG*muG + C1)*(vY + vG + C2));
    f32x2 ssimIG = ((2.f*muI*muG + C1)*(2.f*cIG + C2)) /
                   ((muI*muI + muG*muG + C1)*(vI + vG + C2));

    // block reduce (2 waves) -> per-block partial store (NO atomics)
    float v0 = ssimYG.x + ssimYG.y, v1 = ssimIG.x + ssimIG.y;
    #pragma unroll
    for (int off = 32; off > 0; off >>= 1) {
        v0 += __shfl_down(v0, off);
        v1 += __shfl_down(v1, off);
    }
    __shared__ float red[2][2];
    int lane = tid & 63, wv = tid >> 6;
    if (lane == 0) { red[0][wv] = v0; red[1][wv] = v1; }
    __syncthreads();
    if (tid == 0) {
        parts[3*NBLK + gid] = red[0][0] + red[0][1];
        parts[4*NBLK + gid] = red[1][0] + red[1][1];
    }
}

// ---------------- Sobel-gradient loss + L1 losses ----------------
// Partials (no atomics): parts[0]=loss_in, parts[1]=loss_grad, parts[2]=loss_tra
__global__ __launch_bounds__(256)
void grad_kernel(const float* __restrict__ vis, const float* __restrict__ ir,
                 const float* __restrict__ gen, const float* __restrict__ bf,
                 float* __restrict__ parts) {
    const int idx = blockIdx.x*256 + threadIdx.x;   // NPIX divisible by 256, no guard
    const int b = idx / HWSZ, rem = idx % HWSZ;
    const int y = rem / IMG_W, x = rem % IMG_W;
    const float* py = vis + b*3*HWSZ;
    const float* pi = ir  + b*HWSZ;
    const float* pg = gen + b*HWSZ;
    const float* pb = bf  + b*HWSZ;

    const int ym = (y == 0) ? 1 : y-1, yp = (y == IMG_H-1) ? IMG_H-2 : y+1;
    const int xm = (x == 0) ? 1 : x-1, xp = (x == IMG_W-1) ? IMG_W-2 : x+1;

    float yg = sobel_abs(py, ym, y, yp, xm, x, xp);
    float ig = sobel_abs(pb, ym, y, yp, xm, x, xp);
    float gg = sobel_abs(pg, ym, y, yp, xm, x, xp);
    float tgrad = fabsf(gg - fmaxf(yg, ig));

    float cy = py[y*IMG_W+x], ci = pi[y*IMG_W+x], cg = pg[y*IMG_W+x];
    float tin  = fabsf(cg - fmaxf(cy, ci));
    float ttra = fabsf(cg - 0.5f*(ci + cy));

    float v0 = tin, v1 = tgrad, v2 = ttra;
    #pragma unroll
    for (int off = 32; off > 0; off >>= 1) {
        v0 += __shfl_down(v0, off);
        v1 += __shfl_down(v1, off);
        v2 += __shfl_down(v2, off);
    }
    __shared__ float red[3][4];
    int lane = threadIdx.x & 63, wv = threadIdx.x >> 6;
    if (lane == 0) { red[0][wv] = v0; red[1][wv] = v1; red[2][wv] = v2; }
    __syncthreads();
    if (threadIdx.x == 0) {
        parts[0*NBLK + blockIdx.x] = red[0][0]+red[0][1]+red[0][2]+red[0][3];
        parts[1*NBLK + blockIdx.x] = red[1][0]+red[1][1]+red[1][2]+red[1][3];
        parts[2*NBLK + blockIdx.x] = red[2][0]+red[2][1]+red[2][2]+red[2][3];
    }
}

// ---------------- finalize: reduce 5 x NBLK partials + epilogue ----------------
__global__ __launch_bounds__(256)
void finalize_kernel(const float* __restrict__ parts, float* __restrict__ out) {
    const int tid = threadIdx.x;
    float s0=0,s1=0,s2=0,s3=0,s4=0;
    for (int i = tid; i < NBLK; i += 256) {
        s0 += parts[0*NBLK + i];
        s1 += parts[1*NBLK + i];
        s2 += parts[2*NBLK + i];
        s3 += parts[3*NBLK + i];
        s4 += parts[4*NBLK + i];
    }
    #pragma unroll
    for (int off = 32; off > 0; off >>= 1) {
        s0 += __shfl_down(s0, off);
        s1 += __shfl_down(s1, off);
        s2 += __shfl_down(s2, off);
        s3 += __shfl_down(s3, off);
        s4 += __shfl_down(s4, off);
    }
    __shared__ float red[5][4];
    int lane = tid & 63, wv = tid >> 6;
    if (lane == 0) { red[0][wv]=s0; red[1][wv]=s1; red[2][wv]=s2; red[3][wv]=s3; red[4][wv]=s4; }
    __syncthreads();
    if (tid == 0) {
        const float inv = 1.0f / (float)NPIX;
        float lin   = (red[0][0]+red[0][1]+red[0][2]+red[0][3]) * inv;
        float lgrad = (red[1][0]+red[1][1]+red[1][2]+red[1][3]) * inv;
        float ltra  = (red[2][0]+red[2][1]+red[2][2]+red[2][3]) * inv;
        float ssim1 = (red[3][0]+red[3][1]+red[3][2]+red[3][3]) * inv;
        float ssim2 = (red[4][0]+red[4][1]+red[4][2]+red[4][3]) * inv;
        float lssim = (1.f - ssim1)*0.5f + (1.f - ssim2)*0.5f;
        float ltot  = 10.f*lin + 35.f*lgrad + 1.f*lssim + 10.f*ltra;
        out[0] = ltot; out[1] = lin; out[2] = lgrad; out[3] = lssim; out[4] = ltra;
    }
}

extern "C" void kernel_launch(void* const* d_in, const int* in_sizes, int n_in,
                              void* d_out, int out_size, void* d_ws, size_t ws_size,
                              hipStream_t stream) {
    const float* vis = (const float*)d_in[0];   // (4,3,480,640)
    const float* ir  = (const float*)d_in[1];   // (4,1,480,640)
    const float* gen = (const float*)d_in[2];   // (4,1,480,640)
    float* out = (float*)d_out;                 // 5 fp32 scalars

    float* bf    = (float*)d_ws;                            // NPIX floats
    float* parts = (float*)((char*)d_ws + (size_t)NPIX*4);  // 5*NBLK floats (96 KB)
    // Every parts slot and every bf element is written unconditionally each
    // launch, so no zero-init is needed (harness re-poisons ws with 0xAA).

    dim3 blkB(16, 16);
    dim3 grdB(IMG_W/32, IMG_H/16, IMG_B);   // 20 x 30 x 4
    bilateral_kernel<<<grdB, blkB, 0, stream>>>(ir, bf);

    dim3 blkS(16, 8);
    dim3 grdS(IMG_W/32, IMG_H/8, IMG_B);    // 20 x 60 x 4 = 4800
    ssim_kernel<<<grdS, blkS, 0, stream>>>(vis, ir, gen, parts);
    grad_kernel<<<NBLK, 256, 0, stream>>>(vis, ir, gen, bf, parts);
    finalize_kernel<<<1, 256, 0, stream>>>(parts, out);
}

// Round 8
// 139.643 us; speedup vs baseline: 2.9837x; 1.0316x over previous
//
#include <hip/hip_runtime.h>

#define IMG_H 480
#define IMG_W 640
#define IMG_B 4
#define HWSZ (IMG_H*IMG_W)
#define NPIX (IMG_B*HWSZ)   // 1228800
#define NBLK 4800           // 20*60*4 fused-kernel blocks

typedef float __attribute__((ext_vector_type(2))) f32x2;

// ---------------- constants ----------------
// Normalized 11-tap Gaussian (sigma=1.5) for SSIM window (separable).
constexpr float GW[11] = {
    0.00102838f, 0.00759878f, 0.03600077f, 0.10936067f, 0.21300555f,
    0.26601174f,
    0.21300555f, 0.10936067f, 0.03600077f, 0.00759878f, 0.00102838f};

// log2 of separable spatial weight for bilateral (sigma_space=8)
constexpr float LG2WS[11] = {
    -0.28177637f, -0.18033688f, -0.10143950f, -0.04508422f, -0.01127106f,
    0.0f,
    -0.01127106f, -0.04508422f, -0.10143950f, -0.18033688f, -0.28177637f};
#define C_COLOR (-288.53900818f)   // -200/ln2

__device__ inline float fexp2(float x) {
#if __has_builtin(__builtin_amdgcn_exp2f)
    return __builtin_amdgcn_exp2f(x);
#else
    return exp2f(x);
#endif
}

__device__ inline int refl(int i, int n) {
    // jnp.pad mode='reflect' (overhang <= 5 everywhere here)
    return i < 0 ? -i : (i >= n ? 2*n - 2 - i : i);
}

// sobel |gx|+|gy| for two x-adjacent pixels from a 3x4 neighborhood
__device__ inline f32x2 sobel_pair(const float m[3][4]) {
    f32x2 gx, gy;
    gx.x = (m[0][2] + 2.f*m[1][2] + m[2][2]) - (m[0][0] + 2.f*m[1][0] + m[2][0]);
    gx.y = (m[0][3] + 2.f*m[1][3] + m[2][3]) - (m[0][1] + 2.f*m[1][1] + m[2][1]);
    gy.x = (m[0][0] + 2.f*m[0][1] + m[0][2]) - (m[2][0] + 2.f*m[2][1] + m[2][2]);
    gy.y = (m[0][1] + 2.f*m[0][2] + m[0][3]) - (m[2][1] + 2.f*m[2][2] + m[2][3]);
    f32x2 r;
    r.x = fabsf(gx.x) + fabsf(gy.x);
    r.y = fabsf(gx.y) + fabsf(gy.y);
    return r;
}

// ---------------- bilateral filter of IR ----------------
__global__ __launch_bounds__(256)
void bilateral_kernel(const float* __restrict__ ir, float* __restrict__ bf) {
    __shared__ __attribute__((aligned(16))) float tile[26][42];
    const int tx = threadIdx.x, ty = threadIdx.y;          // 16 x 16
    const int x0 = blockIdx.x*32, y0 = blockIdx.y*16, b = blockIdx.z;
    const float* src = ir + b*HWSZ;
    const int tid = ty*16 + tx;
    for (int i = tid; i < 26*42; i += 256) {
        int r = i / 42, c = i % 42;
        int gy = refl(y0 - 5 + r, IMG_H);
        int gx = refl(x0 - 5 + c, IMG_W);
        tile[r][c] = src[gy*IMG_W + gx];
    }
    __syncthreads();

    const int px = 2*tx;
    f32x2 cen = { tile[ty+5][px+5], tile[ty+5][px+6] };
    f32x2 num = {0.f, 0.f}, den = {0.f, 0.f};
    #pragma unroll
    for (int dy = 0; dy < 11; ++dy) {
        float w[12];
        #pragma unroll
        for (int k = 0; k < 6; ++k) {
            f32x2 p = *reinterpret_cast<const f32x2*>(&tile[ty+dy][px + 2*k]);
            w[2*k] = p.x; w[2*k+1] = p.y;
        }
        #pragma unroll
        for (int dx = 0; dx < 11; ++dx) {
            const float c2 = LG2WS[dy] + LG2WS[dx];
            f32x2 v = { w[dx], w[dx+1] };
            f32x2 d = v - cen;
            f32x2 arg = d*d*C_COLOR + c2;
            f32x2 wt;
            wt.x = fexp2(arg.x);
            wt.y = fexp2(arg.y);
            num += wt*v;
            den += wt;
        }
    }
    f32x2 res = num / den;
    *reinterpret_cast<f32x2*>(&bf[b*HWSZ + (y0+ty)*IMG_W + x0 + px]) = res;
}

// ---------------- fused SSIM + Sobel-grad + L1 losses ----------------
// Block 16x8=128 threads, 32x8 output tile, 2 x-adjacent pixels/thread.
// parts[q*NBLK+gid], q: 0=loss_in 1=loss_grad 2=loss_tra 3=ssimYG 4=ssimIG
__global__ __launch_bounds__(128)
void fused_kernel(const float* __restrict__ vis, const float* __restrict__ ir,
                  const float* __restrict__ gen, const float* __restrict__ bf,
                  float* __restrict__ parts) {
    __shared__ __attribute__((aligned(16))) float sy[18][42], si[18][42], sg[18][42];
    __shared__ __attribute__((aligned(16))) float hs[8][18][34];   // pad 32->34: bank-conflict-free
    const int tx = threadIdx.x, ty = threadIdx.y;          // 16 x 8
    const int x0 = blockIdx.x*32, y0 = blockIdx.y*8, b = blockIdx.z;
    const int tid = ty*16 + tx;                            // 0..127
    const int gid = blockIdx.x + 20*blockIdx.y + 1200*blockIdx.z;  // 0..4799
    const float* py = vis + b*3*HWSZ;   // channel 0 of vis = image_y
    const float* pi = ir  + b*HWSZ;
    const float* pg = gen + b*HWSZ;
    const float* pb = bf  + b*HWSZ;

    // ---- stage zero-padded tiles (SSIM uses zero padding) ----
    for (int i = tid; i < 42*18; i += 128) {
        int r = i / 42, c = i % 42;
        int gy = y0 - 5 + r, gx = x0 - 5 + c;
        bool ok = (gy >= 0) & (gy < IMG_H) & (gx >= 0) & (gx < IMG_W);
        int idx = ok ? gy*IMG_W + gx : 0;
        sy[r][c] = ok ? py[idx] : 0.f;
        si[r][c] = ok ? pi[idx] : 0.f;
        sg[r][c] = ok ? pg[idx] : 0.f;
    }
    __syncthreads();

    // ---- SSIM horizontal pass: 18 rows x 16 column-pairs ----
    for (int i = tid; i < 18*16; i += 128) {
        int r = i / 16, c = 2*(i % 16);
        float wy[12], wi[12], wg[12];
        #pragma unroll
        for (int k = 0; k < 6; ++k) {
            f32x2 p0 = *reinterpret_cast<const f32x2*>(&sy[r][c + 2*k]);
            f32x2 p1 = *reinterpret_cast<const f32x2*>(&si[r][c + 2*k]);
            f32x2 p2 = *reinterpret_cast<const f32x2*>(&sg[r][c + 2*k]);
            wy[2*k] = p0.x; wy[2*k+1] = p0.y;
            wi[2*k] = p1.x; wi[2*k+1] = p1.y;
            wg[2*k] = p2.x; wg[2*k+1] = p2.y;
        }
        f32x2 a0={0,0},a1={0,0},a2={0,0},a3={0,0},a4={0,0},a5={0,0},a6={0,0},a7={0,0};
        #pragma unroll
        for (int dx = 0; dx < 11; ++dx) {
            const float g = GW[dx];
            f32x2 vy = { wy[dx], wy[dx+1] };
            f32x2 vi = { wi[dx], wi[dx+1] };
            f32x2 vg = { wg[dx], wg[dx+1] };
            f32x2 gy = g*vy, gi = g*vi, gg = g*vg;
            a0 += gy;    a1 += gi;    a2 += gg;
            a3 += gy*vy; a4 += gi*vi; a5 += gg*vg;
            a6 += gy*vg; a7 += gi*vg;
        }
        *reinterpret_cast<f32x2*>(&hs[0][r][c]) = a0;
        *reinterpret_cast<f32x2*>(&hs[1][r][c]) = a1;
        *reinterpret_cast<f32x2*>(&hs[2][r][c]) = a2;
        *reinterpret_cast<f32x2*>(&hs[3][r][c]) = a3;
        *reinterpret_cast<f32x2*>(&hs[4][r][c]) = a4;
        *reinterpret_cast<f32x2*>(&hs[5][r][c]) = a5;
        *reinterpret_cast<f32x2*>(&hs[6][r][c]) = a6;
        *reinterpret_cast<f32x2*>(&hs[7][r][c]) = a7;
    }
    __syncthreads();

    // ---- SSIM vertical pass: one pixel-pair per thread ----
    const int px = 2*tx;
    f32x2 s[8];
    #pragma unroll
    for (int f = 0; f < 8; ++f) {
        f32x2 acc = {0.f, 0.f};
        #pragma unroll
        for (int dy = 0; dy < 11; ++dy)
            acc += GW[dy] * (*reinterpret_cast<const f32x2*>(&hs[f][ty+dy][px]));
        s[f] = acc;
    }
    const float C1 = 1e-4f, C2 = 9e-4f;
    f32x2 muY = s[0], muI = s[1], muG = s[2];
    f32x2 vY  = s[3] - muY*muY, vI = s[4] - muI*muI, vG = s[5] - muG*muG;
    f32x2 cYG = s[6] - muY*muG, cIG = s[7] - muI*muG;
    f32x2 ssimYG = ((2.f*muY*muG + C1)*(2.f*cYG + C2)) /
                   ((muY*muY + muG*muG + C1)*(vY + vG + C2));
    f32x2 ssimIG = ((2.f*muI*muG + C1)*(2.f*cIG + C2)) /
                   ((muI*muI + muG*muG + C1)*(vI + vG + C2));

    // ---- grad + L1 phase (global loads, reflect semantics, L1-hot) ----
    const int gxx = x0 + px, gyy = y0 + ty;
    const int xs0 = refl(gxx-1, IMG_W), xs3 = refl(gxx+2, IMG_W);
    const int ys0 = refl(gyy-1, IMG_H), ys2 = refl(gyy+1, IMG_H);
    const int xc[4] = {xs0, gxx, gxx+1, xs3};
    const int yr[3] = {ys0, gyy, ys2};
    float Ym[3][4], Gm[3][4], Bm[3][4];
    #pragma unroll
    for (int r = 0; r < 3; ++r) {
        const int ro = yr[r]*IMG_W;
        #pragma unroll
        for (int c = 0; c < 4; ++c) {
            Ym[r][c] = py[ro + xc[c]];
            Gm[r][c] = pg[ro + xc[c]];
            Bm[r][c] = pb[ro + xc[c]];
        }
    }
    f32x2 ygr = sobel_pair(Ym);
    f32x2 ggr = sobel_pair(Gm);
    f32x2 igr = sobel_pair(Bm);
    f32x2 jg; jg.x = fmaxf(ygr.x, igr.x); jg.y = fmaxf(ygr.y, igr.y);
    f32x2 tgrad; tgrad.x = fabsf(ggr.x - jg.x); tgrad.y = fabsf(ggr.y - jg.y);

    f32x2 cy = { Ym[1][1], Ym[1][2] };
    f32x2 cg = { Gm[1][1], Gm[1][2] };
    f32x2 ci = { pi[gyy*IMG_W + gxx], pi[gyy*IMG_W + gxx + 1] };
    f32x2 tin, ttra;
    tin.x  = fabsf(cg.x - fmaxf(cy.x, ci.x));
    tin.y  = fabsf(cg.y - fmaxf(cy.y, ci.y));
    ttra.x = fabsf(cg.x - 0.5f*(ci.x + cy.x));
    ttra.y = fabsf(cg.y - 0.5f*(ci.y + cy.y));

    // ---- block reduce 5 quantities -> per-block partials (no atomics) ----
    float v0 = tin.x + tin.y;
    float v1 = tgrad.x + tgrad.y;
    float v2 = ttra.x + ttra.y;
    float v3 = ssimYG.x + ssimYG.y;
    float v4 = ssimIG.x + ssimIG.y;
    #pragma unroll
    for (int off = 32; off > 0; off >>= 1) {
        v0 += __shfl_down(v0, off);
        v1 += __shfl_down(v1, off);
        v2 += __shfl_down(v2, off);
        v3 += __shfl_down(v3, off);
        v4 += __shfl_down(v4, off);
    }
    __shared__ float red[5][2];
    int lane = tid & 63, wv = tid >> 6;
    if (lane == 0) { red[0][wv]=v0; red[1][wv]=v1; red[2][wv]=v2; red[3][wv]=v3; red[4][wv]=v4; }
    __syncthreads();
    if (tid == 0) {
        parts[0*NBLK + gid] = red[0][0] + red[0][1];
        parts[1*NBLK + gid] = red[1][0] + red[1][1];
        parts[2*NBLK + gid] = red[2][0] + red[2][1];
        parts[3*NBLK + gid] = red[3][0] + red[3][1];
        parts[4*NBLK + gid] = red[4][0] + red[4][1];
    }
}

// ---------------- finalize: reduce 5 x NBLK partials + epilogue ----------------
__global__ __launch_bounds__(256)
void finalize_kernel(const float* __restrict__ parts, float* __restrict__ out) {
    const int tid = threadIdx.x;
    float s0=0,s1=0,s2=0,s3=0,s4=0;
    for (int i = tid; i < NBLK; i += 256) {
        s0 += parts[0*NBLK + i];
        s1 += parts[1*NBLK + i];
        s2 += parts[2*NBLK + i];
        s3 += parts[3*NBLK + i];
        s4 += parts[4*NBLK + i];
    }
    #pragma unroll
    for (int off = 32; off > 0; off >>= 1) {
        s0 += __shfl_down(s0, off);
        s1 += __shfl_down(s1, off);
        s2 += __shfl_down(s2, off);
        s3 += __shfl_down(s3, off);
        s4 += __shfl_down(s4, off);
    }
    __shared__ float red[5][4];
    int lane = tid & 63, wv = tid >> 6;
    if (lane == 0) { red[0][wv]=s0; red[1][wv]=s1; red[2][wv]=s2; red[3][wv]=s3; red[4][wv]=s4; }
    __syncthreads();
    if (tid == 0) {
        const float inv = 1.0f / (float)NPIX;
        float lin   = (red[0][0]+red[0][1]+red[0][2]+red[0][3]) * inv;
        float lgrad = (red[1][0]+red[1][1]+red[1][2]+red[1][3]) * inv;
        float ltra  = (red[2][0]+red[2][1]+red[2][2]+red[2][3]) * inv;
        float ssim1 = (red[3][0]+red[3][1]+red[3][2]+red[3][3]) * inv;
        float ssim2 = (red[4][0]+red[4][1]+red[4][2]+red[4][3]) * inv;
        float lssim = (1.f - ssim1)*0.5f + (1.f - ssim2)*0.5f;
        float ltot  = 10.f*lin + 35.f*lgrad + 1.f*lssim + 10.f*ltra;
        out[0] = ltot; out[1] = lin; out[2] = lgrad; out[3] = lssim; out[4] = ltra;
    }
}

extern "C" void kernel_launch(void* const* d_in, const int* in_sizes, int n_in,
                              void* d_out, int out_size, void* d_ws, size_t ws_size,
                              hipStream_t stream) {
    const float* vis = (const float*)d_in[0];   // (4,3,480,640)
    const float* ir  = (const float*)d_in[1];   // (4,1,480,640)
    const float* gen = (const float*)d_in[2];   // (4,1,480,640)
    float* out = (float*)d_out;                 // 5 fp32 scalars

    float* bf    = (float*)d_ws;                            // NPIX floats
    float* parts = (float*)((char*)d_ws + (size_t)NPIX*4);  // 5*NBLK floats
    // Every bf element and parts slot is written unconditionally each launch.

    dim3 blkB(16, 16);
    dim3 grdB(IMG_W/32, IMG_H/16, IMG_B);   // 20 x 30 x 4
    bilateral_kernel<<<grdB, blkB, 0, stream>>>(ir, bf);

    dim3 blkF(16, 8);
    dim3 grdF(IMG_W/32, IMG_H/8, IMG_B);    // 20 x 60 x 4 = 4800
    fused_kernel<<<grdF, blkF, 0, stream>>>(vis, ir, gen, bf, parts);
    finalize_kernel<<<1, 256, 0, stream>>>(parts, out);
}